// Round 1
// 211.624 us; speedup vs baseline: 1.0728x; 1.0728x over previous
//
#include <hip/hip_runtime.h>
#include <cstdint>
#include <cstddef>

#define B_ 4
#define C_ 256
#define N_ 4096

typedef __attribute__((ext_vector_type(8))) short s8v;   // 8 bf16 (4 VGPRs) MFMA A/B frag
typedef __attribute__((ext_vector_type(4))) float f4v;   // MFMA C/D frag

#if defined(__has_builtin)
#if __has_builtin(__builtin_amdgcn_exp2f)
#define EXP2(x) __builtin_amdgcn_exp2f(x)
#endif
#endif
#ifndef EXP2
#define EXP2(x) exp2f(x)
#endif

__device__ __forceinline__ unsigned short f2bf(float f) {
  unsigned int u = __builtin_bit_cast(unsigned int, f);
  return (unsigned short)((u + 0x7FFFu + ((u >> 16) & 1u)) >> 16);  // RNE
}

// pack two positive floats to bf16x2 (truncation) in ONE v_perm_b32
__device__ __forceinline__ unsigned pk2bf_trunc(float lo, float hi) {
  return __builtin_amdgcn_perm(__builtin_bit_cast(unsigned, hi),
                               __builtin_bit_cast(unsigned, lo), 0x07060302u);
}

// Blocked fragment layouts (all bf16):
//  xbB/qB/kB/aB: flat = ((b*256 + (n>>4))*32 + (c>>3))*128 + (n&15)*8 + (c&7)
//  vB:           flat = ((((b*64 + (j>>6))*16 + (c>>4))*8 + ((j>>3)&7))*128 + (c&15)*8 + (j&7)

// ---------------- K1: BatchNorm statistics ----------------
__global__ __launch_bounds__(256) void bn_stats(const float* __restrict__ x,
                                                float* __restrict__ mean,
                                                float* __restrict__ rstd) {
  int c = blockIdx.x, t = threadIdx.x;
  float s = 0.f, s2 = 0.f;
  for (int b = 0; b < B_; ++b) {
    const float* p = x + ((size_t)b * C_ + c) * N_;
    for (int n = t; n < N_; n += 256) { float v = p[n]; s += v; s2 += v * v; }
  }
  __shared__ float rs[256], rs2[256];
  rs[t] = s; rs2[t] = s2; __syncthreads();
  for (int off = 128; off > 0; off >>= 1) {
    if (t < off) { rs[t] += rs[t + off]; rs2[t] += rs2[t + off]; }
    __syncthreads();
  }
  if (t == 0) {
    float m = rs[0] * (1.f / 16384.f);
    float v = rs2[0] * (1.f / 16384.f) - m * m;
    mean[c] = m; rstd[c] = rsqrtf(v + 1e-5f);
  }
}

// ---------------- K2: fold BN (and C^-0.5 * log2e into q path) into weights ----------------
__global__ __launch_bounds__(256) void prep(
    const float* __restrict__ wq, const float* __restrict__ bq,
    const float* __restrict__ wk, const float* __restrict__ bk,
    const float* __restrict__ wv, const float* __restrict__ bv,
    const float* __restrict__ wp,
    const float* __restrict__ gamma, const float* __restrict__ beta,
    const float* __restrict__ mean, const float* __restrict__ rstd,
    unsigned short* __restrict__ wqb, unsigned short* __restrict__ wkb,
    unsigned short* __restrict__ wvb, unsigned short* __restrict__ wpb,
    float* __restrict__ beq, float* __restrict__ bek, float* __restrict__ bev) {
  const float QSC = 0.0625f * 1.4426950408889634f;   // C^-0.5 * log2(e)
  int o = blockIdx.x, c = threadIdx.x;
  float a = gamma[c] * rstd[c];
  float d = beta[c] - mean[c] * a;
  float wqv = wq[o * C_ + c], wkv = wk[o * C_ + c], wvv = wv[o * C_ + c];
  wqb[o * C_ + c] = f2bf(wqv * a * QSC);
  wkb[o * C_ + c] = f2bf(wkv * a);
  wvb[o * C_ + c] = f2bf(wvv * a);
  wpb[o * C_ + c] = f2bf(wp[o * C_ + c]);
  __shared__ float r0[256], r1[256], r2[256];
  r0[c] = wqv * d; r1[c] = wkv * d; r2[c] = wvv * d; __syncthreads();
  for (int off = 128; off > 0; off >>= 1) {
    if (c < off) { r0[c] += r0[c + off]; r1[c] += r1[c + off]; r2[c] += r2[c + off]; }
    __syncthreads();
  }
  if (c == 0) {
    beq[o] = (bq[o] + r0[0]) * QSC;
    bek[o] = bk[o] + r1[0];
    bev[o] = bv[o] + r2[0];
  }
}

// ---------------- K2b: x -> blocked bf16 B-fragment layout ----------------
__global__ __launch_bounds__(256) void xt(const float* __restrict__ x,
                                          unsigned short* __restrict__ xbB) {
  int b = blockIdx.z, c0 = blockIdx.y * 64, n0 = blockIdx.x * 64;
  int tid = threadIdx.x;
  __shared__ unsigned short Ls[64][72];
  int cw = tid >> 6, nl = tid & 63;
#pragma unroll
  for (int rr = 0; rr < 16; ++rr) {
    int c = c0 + cw * 16 + rr;
    Ls[nl][cw * 16 + rr] = f2bf(x[((size_t)b * C_ + c) * N_ + n0 + nl]);
  }
  __syncthreads();
  int n_ = tid >> 2, cs = (tid & 3) * 16;
  s8v v0 = *(const s8v*)(&Ls[n_][cs]);
  s8v v1 = *(const s8v*)(&Ls[n_][cs + 8]);
  int n = n0 + n_;
  size_t base = (((size_t)b * 256 + (n >> 4)) * 32 + ((c0 + cs) >> 3)) * 128 + (n & 15) * 8;
  *(s8v*)(xbB + base) = v0;
  *(s8v*)(xbB + base + 128) = v1;
}

// ---------------- K3: fused QKV GEMM (shared x-fragments) ----------------
__global__ __launch_bounds__(256) void qkv(
    const unsigned short* __restrict__ xbB,
    const unsigned short* __restrict__ wqb, const unsigned short* __restrict__ wkb,
    const unsigned short* __restrict__ wvb,
    const float* __restrict__ beq, const float* __restrict__ bek,
    const float* __restrict__ bev,
    unsigned short* __restrict__ qB, unsigned short* __restrict__ kB,
    unsigned short* __restrict__ vB) {
  int b = blockIdx.z, oblk = blockIdx.y, n0 = blockIdx.x * 64;
  int tid = threadIdx.x, w = tid >> 6, l = tid & 63, quad = l >> 4, lq = l & 15;
  int orow = oblk * 64 + w * 16 + lq;

  f4v aq[4], ak[4], av[4];
#pragma unroll
  for (int nt = 0; nt < 4; ++nt) {
    aq[nt] = (f4v){0.f, 0.f, 0.f, 0.f};
    ak[nt] = (f4v){0.f, 0.f, 0.f, 0.f};
    av[nt] = (f4v){0.f, 0.f, 0.f, 0.f};
  }

#pragma unroll
  for (int kk = 0; kk < 8; ++kk) {
    s8v afq = *(const s8v*)(wqb + (size_t)orow * C_ + kk * 32 + quad * 8);
    s8v afk = *(const s8v*)(wkb + (size_t)orow * C_ + kk * 32 + quad * 8);
    s8v afv = *(const s8v*)(wvb + (size_t)orow * C_ + kk * 32 + quad * 8);
#pragma unroll
    for (int nt = 0; nt < 4; ++nt) {
      s8v bf = *(const s8v*)(xbB + (((size_t)b * 256 + ((n0 + nt * 16) >> 4)) * 32 + kk * 4 + quad) * 128 + lq * 8);
      aq[nt] = __builtin_amdgcn_mfma_f32_16x16x32_bf16(afq, bf, aq[nt], 0, 0, 0);
      ak[nt] = __builtin_amdgcn_mfma_f32_16x16x32_bf16(afk, bf, ak[nt], 0, 0, 0);
      av[nt] = __builtin_amdgcn_mfma_f32_16x16x32_bf16(afv, bf, av[nt], 0, 0, 0);
    }
  }

  __shared__ unsigned short Ls[64][72];
  int obase = oblk * 64;

  // pass 1: q -> qB ; pass 2: k -> kB  (both [n][c] blocked)
  for (int pass = 0; pass < 2; ++pass) {
    const f4v* acc = (pass == 0) ? aq : ak;
    const float* BE = (pass == 0) ? beq : bek;
    unsigned short* dst = (pass == 0) ? qB : kB;
    int ob4 = obase + w * 16 + quad * 4;
    float b0 = BE[ob4], b1 = BE[ob4 + 1], b2 = BE[ob4 + 2], b3 = BE[ob4 + 3];
#pragma unroll
    for (int nt = 0; nt < 4; ++nt) {
      unsigned lo = (unsigned)f2bf(acc[nt][0] + b0) | ((unsigned)f2bf(acc[nt][1] + b1) << 16);
      unsigned hi = (unsigned)f2bf(acc[nt][2] + b2) | ((unsigned)f2bf(acc[nt][3] + b3) << 16);
      uint2 pr; pr.x = lo; pr.y = hi;
      *(uint2*)(&Ls[nt * 16 + lq][w * 16 + quad * 4]) = pr;
    }
    __syncthreads();
    {
      int n16rel = tid >> 6, g_rel = (tid >> 3) & 7, lq2 = (tid & 7) * 2;
      s8v v0 = *(const s8v*)(&Ls[n16rel * 16 + lq2][g_rel * 8]);
      s8v v1 = *(const s8v*)(&Ls[n16rel * 16 + lq2 + 1][g_rel * 8]);
      size_t base = (((size_t)b * 256 + (n0 >> 4) + n16rel) * 32 + (obase >> 3) + g_rel) * 128 + lq2 * 8;
      *(s8v*)(dst + base) = v0;
      *(s8v*)(dst + base + 8) = v1;
    }
    __syncthreads();
  }

  // pass 3: v -> vB ([c][n] blocked)
#pragma unroll
  for (int nt = 0; nt < 4; ++nt)
#pragma unroll
    for (int r = 0; r < 4; ++r) {
      int o_ = obase + w * 16 + quad * 4 + r;
      Ls[w * 16 + quad * 4 + r][nt * 16 + lq] = f2bf(av[nt][r] + bev[o_]);
    }
  __syncthreads();
  {
    int cb_rel = tid >> 6, hq = (tid >> 3) & 7, lq2 = (tid & 7) * 2;
    s8v v0 = *(const s8v*)(&Ls[cb_rel * 16 + lq2][hq * 8]);
    s8v v1 = *(const s8v*)(&Ls[cb_rel * 16 + lq2 + 1][hq * 8]);
    size_t base = ((((size_t)b * 64 + (n0 >> 6)) * 16 + oblk * 4 + cb_rel) * 8 + hq) * 128 + lq2 * 8;
    *(s8v*)(vB + base) = v0;
    *(s8v*)(vB + base + 8) = v1;
  }
}

// ---------------- K4: FMHA: 64 q-rows, 16 waves, 256-key chunks ----------------
// K/V L2 traffic halved vs the 32-row version: 256 blocks x (2MB K + 2MB V) = 1.03 GB.
// Per 256-key chunk: each wave owns 16 keys for S (kf, 8 frags) and 16 channels x all
// 256 keys for PV (vf, 8 frags). One barrier per chunk; P double-buffered (2x32KB).
// vf(t) issued before S (lands under 32 S-MFMAs); kf(t+1) issued after the barrier
// (lands under 32 PV-MFMAs; last prefetch reads past kB into vB - benign OOB).
__global__ __launch_bounds__(1024, 4) void attn(
    const unsigned short* __restrict__ qB, const unsigned short* __restrict__ kB,
    const unsigned short* __restrict__ vB, unsigned short* __restrict__ aB) {
  int id = blockIdx.x;                       // 256 blocks; id&7 = XCD (2 XCDs/batch)
  int b = (id & 7) >> 1;
  int i0 = (((id >> 3) << 1) | (id & 1)) << 6;   // 64 q-rows per block
  int tid = threadIdx.x, w = tid >> 6, l = tid & 63, quad = l >> 4, lq = l & 15;

  __shared__ unsigned short Qs[16384];       // 32 KB q-tile (blocked layout)
  __shared__ unsigned short Ps[2][16384];    // 2 x 32 KB P tiles
  __shared__ float Lw[16][4][16];

  // stage q-tile (contiguous 32 KB in qB)
  {
    const s8v* g = (const s8v*)(qB + ((size_t)b * 256 + (i0 >> 4)) * 4096);
    s8v* sq = (s8v*)Qs;
    sq[tid] = g[tid];
    sq[tid + 1024] = g[tid + 1024];
  }

  // per-thread base pointers (element units); in-chunk offsets are constants
  // K: wave w owns keys w*16..w*16+15 of each chunk; +65536/chunk, +kk*512
  const unsigned short* kp = kB + (((size_t)b * 256 + w) * 32 + quad) * 128 + lq * 8;
  // V: wave w owns channels w*16..w*16+15, all 256 keys; +65536/chunk
  const unsigned short* vp = vB + ((size_t)b * 1024 + w) * 1024 + quad * 128 + lq * 8;
  const unsigned short* Qp = Qs + quad * 128 + lq * 8;            // + rg*4096 + kk*512
  // P layout: [key>>3][rg][row&15][key&7] -> kg*512 + rg*128 + lq*8 + k8
  unsigned short* Pw0 = Ps[0] + (w * 2 + (quad >> 1)) * 512 + lq * 8 + (quad & 1) * 4;
  unsigned short* Pw1 = Ps[1] + (w * 2 + (quad >> 1)) * 512 + lq * 8 + (quad & 1) * 4;
  const unsigned short* Pr0 = Ps[0] + quad * 512 + lq * 8;        // + ks*2048 + rg*128
  const unsigned short* Pr1 = Ps[1] + quad * 512 + lq * 8;

  // prologue: kf for chunk 0
  s8v kf[8];
#pragma unroll
  for (int kk = 0; kk < 8; ++kk) kf[kk] = *(const s8v*)(kp + kk * 512);

  __syncthreads();  // Qs visible

  f4v O[4];   // [rg] : channels w*16+quad*4+r, rows i0+rg*16+lq
  O[0] = (f4v){0.f, 0.f, 0.f, 0.f}; O[1] = (f4v){0.f, 0.f, 0.f, 0.f};
  O[2] = (f4v){0.f, 0.f, 0.f, 0.f}; O[3] = (f4v){0.f, 0.f, 0.f, 0.f};
  float lsum[4] = {0.f, 0.f, 0.f, 0.f};

  for (int tt = 0; tt < 8; ++tt) {
#pragma unroll
    for (int half = 0; half < 2; ++half) {
      unsigned short* Pw = half ? Pw1 : Pw0;
      const unsigned short* Pr = half ? Pr1 : Pr0;
      // ---- vf prefetch for THIS chunk (consumed after the barrier) ----
      s8v vf[8];
#pragma unroll
      for (int ks = 0; ks < 8; ++ks)
        vf[ks] = *(const s8v*)(vp + (ks >> 1) * 16384 + (ks & 1) * 512);
      // ---- S phase: this wave's 16 keys x 64 rows (two rg-pair passes) ----
#pragma unroll
      for (int rp = 0; rp < 2; ++rp) {
        f4v St0 = (f4v){0.f, 0.f, 0.f, 0.f};
        f4v St1 = (f4v){0.f, 0.f, 0.f, 0.f};
#pragma unroll
        for (int kk = 0; kk < 8; ++kk) {
          s8v q0 = *(const s8v*)(Qp + (rp * 2 + 0) * 4096 + kk * 512);
          s8v q1 = *(const s8v*)(Qp + (rp * 2 + 1) * 4096 + kk * 512);
          St0 = __builtin_amdgcn_mfma_f32_16x16x32_bf16(kf[kk], q0, St0, 0, 0, 0);
          St1 = __builtin_amdgcn_mfma_f32_16x16x32_bf16(kf[kk], q1, St1, 0, 0, 0);
        }
        {
          float e0 = EXP2(St0[0]), e1 = EXP2(St0[1]), e2 = EXP2(St0[2]), e3 = EXP2(St0[3]);
          lsum[rp * 2] += (e0 + e1) + (e2 + e3);
          uint2 pr; pr.x = pk2bf_trunc(e0, e1); pr.y = pk2bf_trunc(e2, e3);
          *(uint2*)(Pw + (rp * 2) * 128) = pr;
        }
        {
          float e0 = EXP2(St1[0]), e1 = EXP2(St1[1]), e2 = EXP2(St1[2]), e3 = EXP2(St1[3]);
          lsum[rp * 2 + 1] += (e0 + e1) + (e2 + e3);
          uint2 pr; pr.x = pk2bf_trunc(e0, e1); pr.y = pk2bf_trunc(e2, e3);
          *(uint2*)(Pw + (rp * 2 + 1) * 128) = pr;
        }
      }
      __syncthreads();   // P visible; vf already landed (issued before S)
      // ---- kf prefetch for NEXT chunk (lands during PV; last read is benign OOB) ----
      kp += 65536;
#pragma unroll
      for (int kk = 0; kk < 8; ++kk) kf[kk] = *(const s8v*)(kp + kk * 512);
      // ---- PV phase: this wave's 16 channels, all 256 keys ----
#pragma unroll
      for (int ks = 0; ks < 8; ++ks) {
        s8v p0 = *(const s8v*)(Pr + ks * 2048 + 0 * 128);
        s8v p1 = *(const s8v*)(Pr + ks * 2048 + 1 * 128);
        s8v p2 = *(const s8v*)(Pr + ks * 2048 + 2 * 128);
        s8v p3 = *(const s8v*)(Pr + ks * 2048 + 3 * 128);
        O[0] = __builtin_amdgcn_mfma_f32_16x16x32_bf16(vf[ks], p0, O[0], 0, 0, 0);
        O[1] = __builtin_amdgcn_mfma_f32_16x16x32_bf16(vf[ks], p1, O[1], 0, 0, 0);
        O[2] = __builtin_amdgcn_mfma_f32_16x16x32_bf16(vf[ks], p2, O[2], 0, 0, 0);
        O[3] = __builtin_amdgcn_mfma_f32_16x16x32_bf16(vf[ks], p3, O[3], 0, 0, 0);
      }
      vp += 65536;
    }
  }

  // lsum: reduce over quads (keys on rows), publish, sum across the 16 waves
#pragma unroll
  for (int rg = 0; rg < 4; ++rg) {
    lsum[rg] += __shfl_xor(lsum[rg], 16);
    lsum[rg] += __shfl_xor(lsum[rg], 32);
  }
  if (quad == 0) {
    Lw[w][0][lq] = lsum[0]; Lw[w][1][lq] = lsum[1];
    Lw[w][2][lq] = lsum[2]; Lw[w][3][lq] = lsum[3];
  }
  __syncthreads();
  float rl[4];
#pragma unroll
  for (int rg = 0; rg < 4; ++rg) {
    float s = 0.f;
#pragma unroll
    for (int ww = 0; ww < 16; ++ww) s += Lw[ww][rg][lq];
    rl[rg] = 1.f / s;
  }

  // normalize + blocked store (each wave owns its 16 channels; no O combine)
#pragma unroll
  for (int rg = 0; rg < 4; ++rg) {
    ushort4 pk;
    pk.x = f2bf(O[rg][0] * rl[rg]);
    pk.y = f2bf(O[rg][1] * rl[rg]);
    pk.z = f2bf(O[rg][2] * rl[rg]);
    pk.w = f2bf(O[rg][3] * rl[rg]);
    size_t ob = (((size_t)b * 256 + (i0 >> 4) + rg) * 32 + w * 2 + (quad >> 1)) * 128
              + lq * 8 + (quad & 1) * 4;
    *(ushort4*)(aB + ob) = pk;
  }
}

// ---------------- K5: projection + bias + residual ----------------
__global__ __launch_bounds__(256) void proj(
    const float* __restrict__ x, const unsigned short* __restrict__ wpb,
    const float* __restrict__ bp, const unsigned short* __restrict__ aB,
    float* __restrict__ out) {
  int b = blockIdx.z, oblk = blockIdx.y, n0 = blockIdx.x * 64;
  int tid = threadIdx.x, w = tid >> 6, l = tid & 63, quad = l >> 4, lq = l & 15;
  int orow_a = oblk * 64 + w * 16 + lq;

  f4v acc[4];
#pragma unroll
  for (int nt = 0; nt < 4; ++nt) acc[nt] = (f4v){0.f, 0.f, 0.f, 0.f};

#pragma unroll
  for (int kk = 0; kk < 8; ++kk) {
    s8v af = *(const s8v*)(wpb + (size_t)orow_a * C_ + kk * 32 + quad * 8);
#pragma unroll
    for (int nt = 0; nt < 4; ++nt) {
      s8v bf = *(const s8v*)(aB + (((size_t)b * 256 + ((n0 + nt * 16) >> 4)) * 32 + kk * 4 + quad) * 128 + lq * 8);
      acc[nt] = __builtin_amdgcn_mfma_f32_16x16x32_bf16(af, bf, acc[nt], 0, 0, 0);
    }
  }
#pragma unroll
  for (int nt = 0; nt < 4; ++nt)
#pragma unroll
    for (int r = 0; r < 4; ++r) {
      int o_ = oblk * 64 + w * 16 + quad * 4 + r;
      size_t idx = ((size_t)b * C_ + o_) * N_ + n0 + nt * 16 + lq;
      out[idx] = x[idx] + acc[nt][r] + bp[o_];
    }
}

extern "C" void kernel_launch(void* const* d_in, const int* in_sizes, int n_in,
                              void* d_out, int out_size, void* d_ws, size_t ws_size,
                              hipStream_t stream) {
  const float* x     = (const float*)d_in[0];
  const float* gamma = (const float*)d_in[1];
  const float* beta  = (const float*)d_in[2];
  const float* wq    = (const float*)d_in[3];
  const float* bq    = (const float*)d_in[4];
  const float* wk    = (const float*)d_in[5];
  const float* bk    = (const float*)d_in[6];
  const float* wv    = (const float*)d_in[7];
  const float* bv    = (const float*)d_in[8];
  const float* wp    = (const float*)d_in[9];
  const float* bp    = (const float*)d_in[10];
  float* out = (float*)d_out;

  char* ws = (char*)d_ws;
  float* mean = (float*)ws; ws += 1024;
  float* rstd = (float*)ws; ws += 1024;
  float* beq  = (float*)ws; ws += 1024;
  float* bek  = (float*)ws; ws += 1024;
  float* bev  = (float*)ws; ws += 1024;
  unsigned short* wqb = (unsigned short*)ws; ws += C_ * C_ * 2;
  unsigned short* wkb = (unsigned short*)ws; ws += C_ * C_ * 2;
  unsigned short* wvb = (unsigned short*)ws; ws += C_ * C_ * 2;
  unsigned short* wpb = (unsigned short*)ws; ws += C_ * C_ * 2;
  unsigned short* xbB = (unsigned short*)ws; ws += (size_t)B_ * N_ * C_ * 2;
  unsigned short* qB  = (unsigned short*)ws; ws += (size_t)B_ * N_ * C_ * 2;
  unsigned short* kB  = (unsigned short*)ws; ws += (size_t)B_ * N_ * C_ * 2;
  unsigned short* vB  = (unsigned short*)ws; ws += (size_t)B_ * N_ * C_ * 2;
  unsigned short* aB  = (unsigned short*)ws; ws += (size_t)B_ * N_ * C_ * 2;

  hipLaunchKernelGGL(bn_stats, dim3(C_), dim3(256), 0, stream, x, mean, rstd);
  hipLaunchKernelGGL(prep, dim3(C_), dim3(256), 0, stream,
                     wq, bq, wk, bk, wv, bv, wp, gamma, beta, mean, rstd,
                     wqb, wkb, wvb, wpb, beq, bek, bev);
  hipLaunchKernelGGL(xt, dim3(N_ / 64, 4, B_), dim3(256), 0, stream, x, xbB);
  hipLaunchKernelGGL(qkv, dim3(N_ / 64, 4, B_), dim3(256), 0, stream,
                     xbB, wqb, wkb, wvb, beq, bek, bev, qB, kB, vB);
  hipLaunchKernelGGL(attn, dim3(256), dim3(1024), 0, stream, qB, kB, vB, aB);
  hipLaunchKernelGGL(proj, dim3(N_ / 64, 4, B_), dim3(256), 0, stream,
                     x, wpb, bp, aB, out);
}